// Round 2
// baseline (1796.357 us; speedup 1.0000x reference)
//
#include <hip/hip_runtime.h>
#include <math.h>

// Problem constants
// B=2, L=2048, D=1024, H=16, DK=DV=64
static constexpr int Bc = 2;
static constexpr int Lc = 2048;
static constexpr int Dc = 1024;
static constexpr int Hc = 16;
static constexpr int DKc = 64;

// ---------------- block reduction helper (256 threads = 4 waves) -------------
__device__ __forceinline__ float blockReduce(float val, float* red, bool isMax) {
    __syncthreads();  // protect red[] reuse across consecutive calls
    #pragma unroll
    for (int o = 32; o > 0; o >>= 1) {
        float other = __shfl_down(val, o, 64);
        val = isMax ? fmaxf(val, other) : (val + other);
    }
    const int lane = threadIdx.x & 63;
    const int wid = threadIdx.x >> 6;
    if (lane == 0) red[wid] = val;
    __syncthreads();
    if (threadIdx.x == 0) {
        float r = red[0];
        #pragma unroll
        for (int i = 1; i < 4; ++i) r = isMax ? fmaxf(r, red[i]) : (r + red[i]);
        red[0] = r;
    }
    __syncthreads();
    return red[0];
}

// ---------------- QKV projection: Yh[b,h,l,dk] = X(4096x1024) @ W(1024x1024) --
__global__ __launch_bounds__(256) void k_proj(const float* __restrict__ X,
                                              const float* __restrict__ W,
                                              float* __restrict__ Yh) {
    __shared__ float As[16][65];
    __shared__ float Bs[16][64];
    const int tid = threadIdx.x;
    const int tx = tid & 15, ty = tid >> 4;
    const int row0 = blockIdx.x * 64;
    const int col0 = blockIdx.y * 64;
    float acc[4][4] = {};
    for (int kt = 0; kt < Dc; kt += 16) {
        #pragma unroll
        for (int i = 0; i < 4; ++i) {
            int idx = tid + i * 256;
            int m = idx >> 4, kk = idx & 15;
            As[kk][m] = X[(size_t)(row0 + m) * Dc + kt + kk];
        }
        #pragma unroll
        for (int i = 0; i < 4; ++i) {
            int idx = tid + i * 256;
            int kk = idx >> 6, n = idx & 63;
            Bs[kk][n] = W[(size_t)(kt + kk) * (Hc * DKc) + col0 + n];
        }
        __syncthreads();
        #pragma unroll
        for (int kk = 0; kk < 16; ++kk) {
            float a[4], b[4];
            #pragma unroll
            for (int i = 0; i < 4; ++i) a[i] = As[kk][ty * 4 + i];
            #pragma unroll
            for (int j = 0; j < 4; ++j) b[j] = Bs[kk][tx * 4 + j];
            #pragma unroll
            for (int i = 0; i < 4; ++i)
                #pragma unroll
                for (int j = 0; j < 4; ++j) acc[i][j] += a[i] * b[j];
        }
        __syncthreads();
    }
    #pragma unroll
    for (int i = 0; i < 4; ++i) {
        int r = row0 + ty * 4 + i;
        int b = r >> 11, l = r & (Lc - 1);
        #pragma unroll
        for (int j = 0; j < 4; ++j) {
            int c = col0 + tx * 4 + j;
            int h = c >> 6, dk = c & 63;
            Yh[(((size_t)(b * Hc + h) * Lc) + l) * DKc + dk] = acc[i][j];
        }
    }
}

// ---------------- FC projection + residual: Y = AO @ Wfc + RES ---------------
__global__ __launch_bounds__(256) void k_fc(const float* __restrict__ AO,
                                            const float* __restrict__ W,
                                            const float* __restrict__ RES,
                                            float* __restrict__ Y) {
    __shared__ float As[16][65];
    __shared__ float Bs[16][64];
    const int tid = threadIdx.x;
    const int tx = tid & 15, ty = tid >> 4;
    const int row0 = blockIdx.x * 64;
    const int col0 = blockIdx.y * 64;
    float acc[4][4] = {};
    for (int kt = 0; kt < Dc; kt += 16) {
        #pragma unroll
        for (int i = 0; i < 4; ++i) {
            int idx = tid + i * 256;
            int m = idx >> 4, kk = idx & 15;
            As[kk][m] = AO[(size_t)(row0 + m) * Dc + kt + kk];
        }
        #pragma unroll
        for (int i = 0; i < 4; ++i) {
            int idx = tid + i * 256;
            int kk = idx >> 6, n = idx & 63;
            Bs[kk][n] = W[(size_t)(kt + kk) * Dc + col0 + n];
        }
        __syncthreads();
        #pragma unroll
        for (int kk = 0; kk < 16; ++kk) {
            float a[4], b[4];
            #pragma unroll
            for (int i = 0; i < 4; ++i) a[i] = As[kk][ty * 4 + i];
            #pragma unroll
            for (int j = 0; j < 4; ++j) b[j] = Bs[kk][tx * 4 + j];
            #pragma unroll
            for (int i = 0; i < 4; ++i)
                #pragma unroll
                for (int j = 0; j < 4; ++j) acc[i][j] += a[i] * b[j];
        }
        __syncthreads();
    }
    #pragma unroll
    for (int i = 0; i < 4; ++i) {
        int r = row0 + ty * 4 + i;
        #pragma unroll
        for (int j = 0; j < 4; ++j) {
            int c = col0 + tx * 4 + j;
            Y[(size_t)r * Dc + c] = acc[i][j] + RES[(size_t)r * Dc + c];
        }
    }
}

// ---------------- Scores: S[z,q,c] = (Qh[z,q,:]/8) . Kh[z,c,:], masked --------
__global__ __launch_bounds__(256) void k_scores(const float* __restrict__ Qh,
                                                const float* __restrict__ Kh,
                                                const int* __restrict__ mask,
                                                float* __restrict__ attn) {
    __shared__ float Qs[64][65];
    __shared__ float Ks[64][65];
    const int tid = threadIdx.x;
    const int tx = tid & 15, ty = tid >> 4;
    const int z = blockIdx.z;        // b*H + h
    const int b = z >> 4;
    const int q0 = blockIdx.x * 64;
    const int c0 = blockIdx.y * 64;
    const float* Qp = Qh + (size_t)z * Lc * DKc;
    const float* Kp = Kh + (size_t)z * Lc * DKc;
    #pragma unroll
    for (int i = 0; i < 16; ++i) {
        int idx = tid + i * 256;
        int m = idx >> 6, dk = idx & 63;
        Qs[dk][m] = Qp[(size_t)(q0 + m) * DKc + dk];
        Ks[dk][m] = Kp[(size_t)(c0 + m) * DKc + dk];
    }
    __syncthreads();
    float acc[4][4] = {};
    #pragma unroll 8
    for (int kk = 0; kk < 64; ++kk) {
        float a[4], bv[4];
        #pragma unroll
        for (int i = 0; i < 4; ++i) a[i] = Qs[kk][ty * 4 + i];
        #pragma unroll
        for (int j = 0; j < 4; ++j) bv[j] = Ks[kk][tx * 4 + j];
        #pragma unroll
        for (int i = 0; i < 4; ++i)
            #pragma unroll
            for (int j = 0; j < 4; ++j) acc[i][j] += a[i] * bv[j];
    }
    const float scale = 0.125f;  // 1/sqrt(64)
    #pragma unroll
    for (int i = 0; i < 4; ++i) {
        int q = q0 + ty * 4 + i;
        #pragma unroll
        for (int j = 0; j < 4; ++j) {
            int c = c0 + tx * 4 + j;
            float s = acc[i][j] * scale;
            if (mask[((size_t)b * Lc + q) * Lc + c] == 0) s = -1e9f;
            attn[((size_t)z * Lc + q) * Lc + c] = s;
        }
    }
}

// ---------------- Row softmax, in place: rows of length 2048 (float4) --------
__global__ __launch_bounds__(256) void k_softmax(float* __restrict__ attn) {
    __shared__ float red[8];
    float4* p = (float4*)(attn + (size_t)blockIdx.x * Lc);
    const int tid = threadIdx.x;
    float4 v[2];
    float m = -INFINITY;
    #pragma unroll
    for (int j = 0; j < 2; ++j) {
        v[j] = p[tid + j * 256];
        m = fmaxf(m, fmaxf(fmaxf(v[j].x, v[j].y), fmaxf(v[j].z, v[j].w)));
    }
    m = blockReduce(m, red, true);
    float s = 0.f;
    #pragma unroll
    for (int j = 0; j < 2; ++j) {
        v[j].x = __expf(v[j].x - m);
        v[j].y = __expf(v[j].y - m);
        v[j].z = __expf(v[j].z - m);
        v[j].w = __expf(v[j].w - m);
        s += v[j].x + v[j].y + v[j].z + v[j].w;
    }
    s = blockReduce(s, red, false);
    const float inv = 1.0f / s;
    #pragma unroll
    for (int j = 0; j < 2; ++j) {
        v[j].x *= inv; v[j].y *= inv; v[j].z *= inv; v[j].w *= inv;
        p[tid + j * 256] = v[j];
    }
}

// ---------------- PV: AO[b,l,h*64+dv] = sum_k P[z,l,k] * Vh[z,k,dv] ----------
__global__ __launch_bounds__(256) void k_pv(const float* __restrict__ P,
                                            const float* __restrict__ Vh,
                                            float* __restrict__ AO) {
    __shared__ float Ps[32][65];
    __shared__ float Vs[32][64];
    const int tid = threadIdx.x;
    const int tx = tid & 15, ty = tid >> 4;
    const int z = blockIdx.z;
    const int b = z >> 4, h = z & 15;
    const int l0 = blockIdx.x * 64;
    const float* Pp = P + (size_t)z * Lc * Lc;
    const float* Vp = Vh + (size_t)z * Lc * DKc;
    float acc[4][4] = {};
    for (int kt = 0; kt < Lc; kt += 32) {
        #pragma unroll
        for (int i = 0; i < 8; ++i) {
            int idx = tid + i * 256;
            int m = idx >> 5, kk = idx & 31;
            Ps[kk][m] = Pp[(size_t)(l0 + m) * Lc + kt + kk];
        }
        #pragma unroll
        for (int i = 0; i < 8; ++i) {
            int idx = tid + i * 256;
            int kk = idx >> 6, n = idx & 63;
            Vs[kk][n] = Vp[(size_t)(kt + kk) * DKc + n];
        }
        __syncthreads();
        #pragma unroll
        for (int kk = 0; kk < 32; ++kk) {
            float a[4], bv[4];
            #pragma unroll
            for (int i = 0; i < 4; ++i) a[i] = Ps[kk][ty * 4 + i];
            #pragma unroll
            for (int j = 0; j < 4; ++j) bv[j] = Vs[kk][tx * 4 + j];
            #pragma unroll
            for (int i = 0; i < 4; ++i)
                #pragma unroll
                for (int j = 0; j < 4; ++j) acc[i][j] += a[i] * bv[j];
        }
        __syncthreads();
    }
    #pragma unroll
    for (int i = 0; i < 4; ++i) {
        int l = l0 + ty * 4 + i;
        #pragma unroll
        for (int j = 0; j < 4; ++j) {
            int dv = tx * 4 + j;
            AO[((size_t)(b * Lc + l)) * Dc + h * DKc + dv] = acc[i][j];
        }
    }
}

// ---------------- LayerNorm over D=1024 (float4) -----------------------------
__global__ __launch_bounds__(256) void k_ln(const float* __restrict__ X,
                                            const float* __restrict__ g,
                                            const float* __restrict__ bta,
                                            float* __restrict__ Y) {
    __shared__ float red[8];
    const int row = blockIdx.x;
    const float4* x = (const float4*)(X + (size_t)row * Dc);
    const float4* g4 = (const float4*)g;
    const float4* b4 = (const float4*)bta;
    float4* y = (float4*)(Y + (size_t)row * Dc);
    const int tid = threadIdx.x;
    float4 v = x[tid];
    float s = v.x + v.y + v.z + v.w;
    float ss = v.x * v.x + v.y * v.y + v.z * v.z + v.w * v.w;
    s = blockReduce(s, red, false);
    ss = blockReduce(ss, red, false);
    const float mu = s * (1.0f / Dc);
    const float var = ss * (1.0f / Dc) - mu * mu;
    const float inv = rsqrtf(var + 1e-6f);
    float4 gv = g4[tid], bv = b4[tid], o;
    o.x = (v.x - mu) * inv * gv.x + bv.x;
    o.y = (v.y - mu) * inv * gv.y + bv.y;
    o.z = (v.z - mu) * inv * gv.z + bv.z;
    o.w = (v.w - mu) * inv * gv.w + bv.w;
    y[tid] = o;
}

extern "C" void kernel_launch(void* const* d_in, const int* in_sizes, int n_in,
                              void* d_out, int out_size, void* d_ws, size_t ws_size,
                              hipStream_t stream) {
    const float* q    = (const float*)d_in[0];
    const float* k    = (const float*)d_in[1];
    const float* v    = (const float*)d_in[2];
    const int*   mask = (const int*)d_in[3];
    const float* w_q  = (const float*)d_in[4];
    const float* w_k  = (const float*)d_in[5];
    const float* w_v  = (const float*)d_in[6];
    const float* w_fc = (const float*)d_in[7];
    const float* ln_g = (const float*)d_in[8];
    const float* ln_b = (const float*)d_in[9];

    float* out  = (float*)d_out;                       // (B,L,D) = 4,194,304
    float* attn = out + (size_t)Bc * Lc * Dc;          // (B,H,L,L)

    float* ws = (float*)d_ws;
    const size_t SLOT = (size_t)Bc * Hc * Lc * DKc;    // 4,194,304 floats (16 MB)
    float* qh   = ws;                                  // slot 0
    float* kh   = ws + SLOT;                           // slot 1
    float* vh   = ws + 2 * SLOT;                       // slot 2
    float* ao   = ws;                                  // reuse slot 0 (qh dead after scores)
    float* proj = ws + SLOT;                           // reuse slot 1 (kh dead after scores)

    dim3 blk(256);
    dim3 gProj(64, 16);   // M=4096/64, N=1024/64

    k_proj<<<gProj, blk, 0, stream>>>(q, w_q, qh);
    k_proj<<<gProj, blk, 0, stream>>>(k, w_k, kh);
    k_proj<<<gProj, blk, 0, stream>>>(v, w_v, vh);

    k_scores<<<dim3(32, 32, 32), blk, 0, stream>>>(qh, kh, mask, attn);
    k_softmax<<<dim3(Bc * Hc * Lc), blk, 0, stream>>>(attn);
    k_pv<<<dim3(32, 1, 32), blk, 0, stream>>>(attn, vh, ao);

    k_fc<<<gProj, blk, 0, stream>>>(ao, w_fc, q, proj);
    k_ln<<<dim3(Bc * Lc), blk, 0, stream>>>(proj, ln_g, ln_b, out);
}